// Round 1
// baseline (366.142 us; speedup 1.0000x reference)
//
#include <hip/hip_runtime.h>
#include <math.h>

#define WAVE 64

// ---------------------------------------------------------------------------
// Kernel 1: mids[b,k] = sum_q W[k,q] * query[b,q]
// One wave per (b,k) output. Q=512 -> 128 float4 -> 2 float4 per lane.
// W rows are re-read B=64 times but W is 1 MB total -> L2-resident.
// ---------------------------------------------------------------------------
__global__ void mids_kernel(const float* __restrict__ W,
                            const float* __restrict__ query,
                            float* __restrict__ mids,
                            int B, int K, int Q) {
    int gwave = (int)((blockIdx.x * blockDim.x + threadIdx.x) / WAVE);
    int lane  = threadIdx.x & (WAVE - 1);
    int total = B * K;
    if (gwave >= total) return;
    int b = gwave / K;
    int k = gwave - b * K;

    const float4* wrow = (const float4*)(W + (size_t)k * Q);
    const float4* qrow = (const float4*)(query + (size_t)b * Q);

    float acc = 0.f;
    int nvec = Q >> 2;  // 128
    for (int i = lane; i < nvec; i += WAVE) {
        float4 w = wrow[i];
        float4 q = qrow[i];
        acc += w.x * q.x + w.y * q.y + w.z * q.z + w.w * q.w;
    }
    #pragma unroll
    for (int off = 32; off > 0; off >>= 1)
        acc += __shfl_down(acc, off, WAVE);
    if (lane == 0) mids[gwave] = acc;
}

// ---------------------------------------------------------------------------
// Kernel 2: scores[b,t] = tanhf(sum_k key[b,t,k] * mids[b,k] + bias)
// One wave per (b,t) row. K=512 -> 128 float4 -> exactly 2 float4 per lane.
// key read is the 268 MB that dominates the whole problem; fully coalesced
// 16 B/lane loads. mids[b] (2 KB) is L1-hot across the 2048 rows of a batch.
// ---------------------------------------------------------------------------
__global__ void scores_kernel(const float* __restrict__ key,
                              const float* __restrict__ mids,
                              const float* __restrict__ bias,
                              float* __restrict__ scores,
                              int B, int T, int K) {
    int gwave = (int)((blockIdx.x * blockDim.x + threadIdx.x) / WAVE);
    int lane  = threadIdx.x & (WAVE - 1);
    int total = B * T;
    if (gwave >= total) return;
    int b = gwave / T;

    const float4* krow = (const float4*)(key  + (size_t)gwave * K);
    const float4* mrow = (const float4*)(mids + (size_t)b * K);

    float acc = 0.f;
    #pragma unroll
    for (int i = 0; i < 2; ++i) {   // 512/4/64 == 2
        int idx = lane + i * WAVE;
        float4 kk = krow[idx];
        float4 mm = mrow[idx];
        acc += kk.x * mm.x + kk.y * mm.y + kk.z * mm.z + kk.w * mm.w;
    }
    #pragma unroll
    for (int off = 32; off > 0; off >>= 1)
        acc += __shfl_down(acc, off, WAVE);
    if (lane == 0) scores[gwave] = tanhf(acc + bias[0]);
}

// ---------------------------------------------------------------------------
// Kernel 3: in-place softmax over T=2048 per batch row. 64 blocks x 256 thr.
// Each thread keeps its 8 values in registers (no second global read pass
// until the final scaled write).
// ---------------------------------------------------------------------------
__global__ void softmax_kernel(float* __restrict__ out, int T) {
    const int b   = blockIdx.x;
    const int tid = threadIdx.x;
    const int lane = tid & (WAVE - 1);
    const int wid  = tid >> 6;          // 4 waves per block
    float* row = out + (size_t)b * T;

    __shared__ float red[4];

    float vals[8];
    float m = -INFINITY;
    #pragma unroll
    for (int i = 0; i < 8; ++i) {
        vals[i] = row[tid + i * 256];
        m = fmaxf(m, vals[i]);
    }
    #pragma unroll
    for (int off = 32; off > 0; off >>= 1)
        m = fmaxf(m, __shfl_down(m, off, WAVE));
    if (lane == 0) red[wid] = m;
    __syncthreads();
    m = fmaxf(fmaxf(red[0], red[1]), fmaxf(red[2], red[3]));
    __syncthreads();

    float s = 0.f;
    #pragma unroll
    for (int i = 0; i < 8; ++i) {
        vals[i] = expf(vals[i] - m);
        s += vals[i];
    }
    #pragma unroll
    for (int off = 32; off > 0; off >>= 1)
        s += __shfl_down(s, off, WAVE);
    if (lane == 0) red[wid] = s;
    __syncthreads();
    s = red[0] + red[1] + red[2] + red[3];

    float inv = 1.f / s;
    #pragma unroll
    for (int i = 0; i < 8; ++i)
        row[tid + i * 256] = vals[i] * inv;
}

// ---------------------------------------------------------------------------
extern "C" void kernel_launch(void* const* d_in, const int* in_sizes, int n_in,
                              void* d_out, int out_size, void* d_ws, size_t ws_size,
                              hipStream_t stream) {
    const float* query = (const float*)d_in[0];   // [B, Q]
    const float* key   = (const float*)d_in[1];   // [B, T, K]
    const float* W     = (const float*)d_in[2];   // [K, Q]
    const float* bias  = (const float*)d_in[3];   // [1]
    float* out  = (float*)d_out;                  // [B, T]
    float* mids = (float*)d_ws;                   // [B, K] scratch (128 KB)

    const int B = 64, T = 2048, Q = 512, K = 512;

    // 1) mids: B*K = 32768 waves, 4 waves/block -> 8192 blocks
    mids_kernel<<<(B * K) / 4, 256, 0, stream>>>(W, query, mids, B, K, Q);

    // 2) scores: B*T = 131072 waves, 4 waves/block -> 32768 blocks
    scores_kernel<<<(B * T) / 4, 256, 0, stream>>>(key, mids, bias, out, B, T, K);

    // 3) softmax: one block per batch row
    softmax_kernel<<<B, 256, 0, stream>>>(out, T);
}